// Round 2
// baseline (408.716 us; speedup 1.0000x reference)
//
#include <hip/hip_runtime.h>

// Inclusive prefix-sum along L of X[B=8][L=4096][D=64][N=16] fp32.
// Single-pass decoupled-lookback scan: one read + one write of 134 MB.

constexpr int BB = 8;
constexpr int LL = 4096;
constexpr int DN = 1024;          // D*N, contiguous per (b,l)
constexpr int T  = 32;            // rows per tile (held in registers)
constexpr int CT = LL / T;        // 128 tiles per chain
constexpr int NTILES = BB * CT;   // 1024
constexpr int TPB = 256;          // each thread owns one float4 column (4 dn)

typedef unsigned long long u64;

__device__ __forceinline__ u64 pack2(float a, float b) {
    union { float f[2]; u64 u; } x; x.f[0] = a; x.f[1] = b; return x.u;
}
__device__ __forceinline__ float2 unpack2(u64 v) {
    union { float f[2]; u64 u; } x; x.u = v; return make_float2(x.f[0], x.f[1]);
}

__global__ __launch_bounds__(TPB) void scan_lookback(
    const float* __restrict__ x, float* __restrict__ out,
    unsigned* __restrict__ counter, unsigned* __restrict__ flags,
    float* __restrict__ payload) {

    // Dynamic tile id: guarantees the minimal unfinished tile can always
    // progress (predecessors have smaller ids -> already finished or resident).
    __shared__ unsigned s_vid;
    if (threadIdx.x == 0)
        s_vid = __hip_atomic_fetch_add(counter, 1u, __ATOMIC_RELAXED,
                                       __HIP_MEMORY_SCOPE_AGENT);
    __syncthreads();
    const unsigned vid = s_vid;
    const int b = vid & (BB - 1);   // vids 0..7 are the 8 chain heads
    const int c = vid >> 3;
    const int t = threadIdx.x;

    const size_t base = (size_t)b * LL * DN + (size_t)c * T * DN;
    const float4* xp = reinterpret_cast<const float4*>(x + base) + t;
    float4 v[T];
    #pragma unroll
    for (int i = 0; i < T; ++i) v[i] = xp[i * (DN / 4)];
    #pragma unroll
    for (int i = 1; i < T; ++i) {
        v[i].x += v[i-1].x; v[i].y += v[i-1].y;
        v[i].z += v[i-1].z; v[i].w += v[i-1].w;
    }

    // payload slot: [0..1023] inclusive, [1024..2047] aggregate
    float* slot = payload + (size_t)vid * 2048;
    u64* pubp = (u64*)(slot + (c == 0 ? 0 : 1024)) + t * 2;
    __hip_atomic_store(pubp,     pack2(v[T-1].x, v[T-1].y),
                       __ATOMIC_RELAXED, __HIP_MEMORY_SCOPE_AGENT);
    __hip_atomic_store(pubp + 1, pack2(v[T-1].z, v[T-1].w),
                       __ATOMIC_RELAXED, __HIP_MEMORY_SCOPE_AGENT);
    __syncthreads();   // compiler drains vmcnt before s_barrier -> stores visible
    if (t == 0)
        __hip_atomic_store(&flags[vid], (c == 0) ? 2u : 1u,
                           __ATOMIC_RELEASE, __HIP_MEMORY_SCOPE_AGENT);

    float4 off = make_float4(0.f, 0.f, 0.f, 0.f);
    if (c > 0) {
        int p = (int)vid - BB;
        for (;;) {
            unsigned f;
            do {
                f = __hip_atomic_load(&flags[p], __ATOMIC_ACQUIRE,
                                      __HIP_MEMORY_SCOPE_AGENT);
            } while (f == 0);
            const u64* pp = (const u64*)(payload + (size_t)p * 2048 +
                                         (f == 1 ? 1024 : 0)) + t * 2;
            u64 a0 = __hip_atomic_load(pp,     __ATOMIC_RELAXED, __HIP_MEMORY_SCOPE_AGENT);
            u64 a1 = __hip_atomic_load(pp + 1, __ATOMIC_RELAXED, __HIP_MEMORY_SCOPE_AGENT);
            float2 f0 = unpack2(a0), f1 = unpack2(a1);
            off.x += f0.x; off.y += f0.y; off.z += f1.x; off.w += f1.y;
            if (f == 2) break;     // hit an inclusive prefix -> done
            p -= BB;               // else keep hopping aggregates
        }
        // publish our inclusive so successors short-circuit
        u64* ip = (u64*)slot + t * 2;
        __hip_atomic_store(ip,     pack2(off.x + v[T-1].x, off.y + v[T-1].y),
                           __ATOMIC_RELAXED, __HIP_MEMORY_SCOPE_AGENT);
        __hip_atomic_store(ip + 1, pack2(off.z + v[T-1].z, off.w + v[T-1].w),
                           __ATOMIC_RELAXED, __HIP_MEMORY_SCOPE_AGENT);
        __syncthreads();
        if (t == 0)
            __hip_atomic_store(&flags[vid], 2u,
                               __ATOMIC_RELEASE, __HIP_MEMORY_SCOPE_AGENT);
    }

    float4* op = reinterpret_cast<float4*>(out + base) + t;
    #pragma unroll
    for (int i = 0; i < T; ++i) {
        float4 r = v[i];
        r.x += off.x; r.y += off.y; r.z += off.z; r.w += off.w;
        op[i * (DN / 4)] = r;
    }
}

extern "C" void kernel_launch(void* const* d_in, const int* in_sizes, int n_in,
                              void* d_out, int out_size, void* d_ws, size_t ws_size,
                              hipStream_t stream) {
    const float* x = (const float*)d_in[0];
    float* out = (float*)d_out;

    // ws layout: [0..3] counter | [64..64+4*NTILES) flags | [8192..) payload
    unsigned* counter = (unsigned*)d_ws;
    unsigned* flags   = (unsigned*)((char*)d_ws + 64);
    float*    payload = (float*)((char*)d_ws + 8192);   // NTILES * 8 KB = 8 MB

    // zero control block every launch (graph-capturable)
    hipMemsetAsync(d_ws, 0, 8192, stream);
    scan_lookback<<<dim3(NTILES), dim3(TPB), 0, stream>>>(x, out, counter, flags, payload);
}

// Round 4
// 367.121 us; speedup vs baseline: 1.1133x; 1.1133x over previous
//
#include <hip/hip_runtime.h>

// Inclusive prefix-sum along L of X[B=8][L=4096][D=64][N=16] fp32.
// Single-pass, in-register tiles + all-gather of tile aggregates.
// No serial flag chains: tile (b,c) sums the c independent aggregates itself.

constexpr int BB = 8;
constexpr int LL = 4096;
constexpr int DN = 1024;          // D*N, contiguous per (b,l)
constexpr int T  = 32;            // rows per tile, held in registers
constexpr int CT = LL / T;        // 128 tiles per chain
constexpr int NT = BB * CT;       // 1024 tiles
constexpr int TPB = 512;          // each thread owns one float2 column pair

typedef unsigned long long u64;

__device__ __forceinline__ u64 pack2(float a, float b) {
    union { float f[2]; u64 u; } x; x.f[0] = a; x.f[1] = b; return x.u;
}
__device__ __forceinline__ float2 unpack2(u64 v) {
    union { float f[2]; u64 u; } x; x.u = v; return make_float2(x.f[0], x.f[1]);
}

__global__ __launch_bounds__(TPB) void scan_allgather(
    const float* __restrict__ x, float* __restrict__ out,
    unsigned* __restrict__ counter, unsigned* __restrict__ flags,
    float* __restrict__ csum) {

    // Dynamic tile id (chunk-major): predecessors always have smaller ids ->
    // resident or finished -> they publish aggregates without waiting -> no deadlock.
    __shared__ unsigned s_vid;
    if (threadIdx.x == 0)
        s_vid = __hip_atomic_fetch_add(counter, 1u, __ATOMIC_RELAXED,
                                       __HIP_MEMORY_SCOPE_AGENT);
    __syncthreads();
    const unsigned vid = s_vid;
    const int b = vid & (BB - 1);
    const int c = vid >> 3;
    const int t = threadIdx.x;

    const size_t base = (size_t)b * LL * DN + (size_t)c * T * DN;
    const float2* xp = reinterpret_cast<const float2*>(x + base) + t;
    float2 v[T];
    #pragma unroll
    for (int i = 0; i < T; ++i) v[i] = xp[i * (DN / 2)];
    #pragma unroll
    for (int i = 1; i < T; ++i) { v[i].x += v[i-1].x; v[i].y += v[i-1].y; }

    // Publish this tile's aggregate (last chunk's aggregate is never consumed).
    if (c + 1 < CT) {
        u64* pp = (u64*)(csum + (size_t)vid * DN) + t;
        __hip_atomic_store(pp, pack2(v[T-1].x, v[T-1].y),
                           __ATOMIC_RELAXED, __HIP_MEMORY_SCOPE_AGENT);
        __syncthreads();           // all waves' stores complete before flag
        if (t == 0) {
            __threadfence();       // release: csum stores visible before flag
            __hip_atomic_store(&flags[vid], 1u,
                               __ATOMIC_RELEASE, __HIP_MEMORY_SCOPE_AGENT);
        }
    }

    float2 off = make_float2(0.f, 0.f);
    if (c > 0) {
        // Distributed spin: thread j waits for predecessor chunk j's flag.
        for (int j = t; j < c; j += TPB) {
            while (__hip_atomic_load(&flags[(j << 3) + b], __ATOMIC_RELAXED,
                                     __HIP_MEMORY_SCOPE_AGENT) == 0u)
                __builtin_amdgcn_s_sleep(1);
        }
        __syncthreads();
        __threadfence();           // acquire: flags seen -> csum loads not stale
        // Gather: c independent, pipelined LLC loads per thread.
        const u64* cs = (const u64*)csum + t;
        #pragma unroll 4
        for (int j = 0; j < c; ++j) {
            u64 a = __hip_atomic_load(cs + (size_t)((j << 3) + b) * (DN / 2),
                                      __ATOMIC_RELAXED, __HIP_MEMORY_SCOPE_AGENT);
            float2 f = unpack2(a);
            off.x += f.x; off.y += f.y;
        }
    }

    float2* op = reinterpret_cast<float2*>(out + base) + t;
    #pragma unroll
    for (int i = 0; i < T; ++i) {
        float2 r = v[i];
        r.x += off.x; r.y += off.y;
        op[i * (DN / 2)] = r;
    }
}

extern "C" void kernel_launch(void* const* d_in, const int* in_sizes, int n_in,
                              void* d_out, int out_size, void* d_ws, size_t ws_size,
                              hipStream_t stream) {
    const float* x = (const float*)d_in[0];
    float* out = (float*)d_out;

    // ws: [0..3] counter | [64..64+4*NT) flags | [8192..) csum (NT*4KB = 4MB)
    unsigned* counter = (unsigned*)d_ws;
    unsigned* flags   = (unsigned*)((char*)d_ws + 64);
    float*    csum    = (float*)((char*)d_ws + 8192);

    (void)hipMemsetAsync(d_ws, 0, 8192, stream);   // zero control block each launch
    scan_allgather<<<dim3(NT), dim3(TPB), 0, stream>>>(x, out, counter, flags, csum);
}

// Round 5
// 87.192 us; speedup vs baseline: 4.6875x; 4.2105x over previous
//
#include <hip/hip_runtime.h>

// Inclusive prefix-sum along L of X[B=8][L=4096][D=64][N=16] fp32.
// 3-pass reduce-then-scan. dn = d*16+n contiguous (1024 floats per (b,l)).

typedef float f2 __attribute__((ext_vector_type(2)));
typedef float f4 __attribute__((ext_vector_type(4)));

constexpr int BB = 8;
constexpr int LL = 4096;
constexpr int DN = 1024;       // D*N
constexpr int C  = 128;        // chunks per column
constexpr int S  = LL / C;     // 32 rows per chunk

// P1: per-chunk column sums. 1024 blocks x 256 thr; thread owns one float4 col.
__global__ __launch_bounds__(256) void p1(const float* __restrict__ x,
                                          float* __restrict__ csum) {
    const int bid = blockIdx.x;            // b*C + c
    const int b = bid >> 7, c = bid & (C - 1);
    const int t = threadIdx.x;
    const f4* xp = reinterpret_cast<const f4*>(
        x + (size_t)b * LL * DN + (size_t)c * S * DN) + t;
    f4 acc = (f4)0.f;
    #pragma unroll
    for (int i = 0; i < S; ++i) acc += xp[i * (DN / 4)];
    reinterpret_cast<f4*>(csum + (size_t)bid * DN)[t] = acc;
}

// P2: exclusive scan of the C chunk sums per (b, dn) scalar column.
// 8192 threads; all 128 loads issued independently before the serial scan.
__global__ __launch_bounds__(512) void p2(float* __restrict__ csum) {
    const int gid = blockIdx.x * 512 + threadIdx.x;   // 0 .. B*DN-1
    const int b = gid >> 10, dn = gid & (DN - 1);
    float* base = csum + (size_t)b * C * DN + dn;
    float v[C];
    #pragma unroll
    for (int c = 0; c < C; ++c) v[c] = base[(size_t)c * DN];
    float run = 0.f;
    #pragma unroll
    for (int c = 0; c < C; ++c) { float tv = v[c]; base[(size_t)c * DN] = run; run += tv; }
}

// P3: running scan per chunk from exclusive offset; nontemporal output so the
// 134 MB write stream doesn't evict x from L3 (x re-read should be L3-hit).
__global__ __launch_bounds__(512) void p3(const float* __restrict__ x,
                                          const float* __restrict__ csum,
                                          float* __restrict__ out) {
    const int bid = blockIdx.x;
    const int b = bid >> 7, c = bid & (C - 1);
    const int t = threadIdx.x;                       // float2 column pair
    const size_t base = (size_t)b * LL * DN + (size_t)c * S * DN;
    const f2* xp = reinterpret_cast<const f2*>(x + base) + t;
    f2* op = reinterpret_cast<f2*>(out + base) + t;
    f2 run = reinterpret_cast<const f2*>(csum + (size_t)bid * DN)[t];
    #pragma unroll
    for (int i = 0; i < S; ++i) {
        run += xp[i * (DN / 2)];
        __builtin_nontemporal_store(run, op + i * (DN / 2));
    }
}

extern "C" void kernel_launch(void* const* d_in, const int* in_sizes, int n_in,
                              void* d_out, int out_size, void* d_ws, size_t ws_size,
                              hipStream_t stream) {
    const float* x = (const float*)d_in[0];
    float* out = (float*)d_out;
    float* csum = (float*)d_ws;    // B*C*DN*4 = 4 MiB, fully overwritten by P1

    p1<<<dim3(BB * C), dim3(256), 0, stream>>>(x, csum);
    p2<<<dim3(BB * DN / 512), dim3(512), 0, stream>>>(csum);
    p3<<<dim3(BB * C), dim3(512), 0, stream>>>(x, csum, out);
}

// Round 6
// 68.848 us; speedup vs baseline: 5.9365x; 1.2664x over previous
//
#include <hip/hip_runtime.h>

// Inclusive prefix-sum along L of X[B=8][L=4096][D=64][N=16] fp32.
// 2-pass reduce-then-scan. dn = d*16+n contiguous (1024 floats per (b,l)).
// K1: per-chunk column sums -> csum.  K2: block (b,c) sums csum[b,0..c-1]
// itself (kernel boundary = sync; csum is L2/LLC-resident), then streams.

typedef float f4 __attribute__((ext_vector_type(4)));

constexpr int BB = 8;
constexpr int LL = 4096;
constexpr int DN = 1024;       // D*N
constexpr int C  = 64;         // chunks per column
constexpr int S  = LL / C;     // 64 rows per chunk
constexpr int TPB = 256;       // thread owns one float4 column group

// K1: per-chunk column sums. 512 blocks x 256 thr.
__global__ __launch_bounds__(TPB) void k1(const float* __restrict__ x,
                                          float* __restrict__ csum) {
    const int bid = blockIdx.x;            // b*C + c
    const int b = bid >> 6, c = bid & (C - 1);
    const int t = threadIdx.x;
    const f4* xp = reinterpret_cast<const f4*>(
        x + (size_t)b * LL * DN + (size_t)c * S * DN) + t;
    f4 acc = (f4)0.f;
    #pragma unroll 8
    for (int i = 0; i < S; ++i) acc += xp[i * (DN / 4)];
    reinterpret_cast<f4*>(csum + (size_t)bid * DN)[t] = acc;
}

// K2: gather exclusive offset from csum, then running scan + write.
__global__ __launch_bounds__(TPB) void k2(const float* __restrict__ x,
                                          const float* __restrict__ csum,
                                          float* __restrict__ out) {
    const int bid = blockIdx.x;
    const int b = bid >> 6, c = bid & (C - 1);
    const int t = threadIdx.x;

    // Exclusive offset: sum of this batch's preceding chunk aggregates.
    // c independent cache-resident loads, pipelined.
    f4 run = (f4)0.f;
    const f4* cs = reinterpret_cast<const f4*>(csum + (size_t)(b * C) * DN) + t;
    #pragma unroll 4
    for (int j = 0; j < c; ++j) run += cs[j * (DN / 4)];

    const size_t base = (size_t)b * LL * DN + (size_t)c * S * DN;
    const f4* xp = reinterpret_cast<const f4*>(x + base) + t;
    f4* op = reinterpret_cast<f4*>(out + base) + t;
    #pragma unroll 4
    for (int i = 0; i < S; ++i) {
        run += xp[i * (DN / 4)];
        op[i * (DN / 4)] = run;
    }
}

extern "C" void kernel_launch(void* const* d_in, const int* in_sizes, int n_in,
                              void* d_out, int out_size, void* d_ws, size_t ws_size,
                              hipStream_t stream) {
    const float* x = (const float*)d_in[0];
    float* out = (float*)d_out;
    float* csum = (float*)d_ws;    // B*C*DN*4 = 2 MiB, fully overwritten by K1

    k1<<<dim3(BB * C), dim3(TPB), 0, stream>>>(x, csum);
    k2<<<dim3(BB * C), dim3(TPB), 0, stream>>>(x, csum, out);
}

// Round 7
// 67.291 us; speedup vs baseline: 6.0738x; 1.0231x over previous
//
#include <hip/hip_runtime.h>

// Inclusive prefix-sum along L of X[B=8][L=4096][D=64][N=16] fp32.
// 2-pass reduce-then-scan. dn = d*16+n contiguous (1024 floats per (b,l)).
// K1: per-chunk column sums -> csum.  K2: block (b,c) sums csum[b,0..c-1]
// itself (kernel boundary = sync; csum is L2/LLC-resident), then streams.
// This round's single change: K2 stores are NONTEMPORAL so the 134 MB write
// stream doesn't evict x from the Infinity Cache (x re-read should L3-hit).

typedef float f4 __attribute__((ext_vector_type(4)));

constexpr int BB = 8;
constexpr int LL = 4096;
constexpr int DN = 1024;       // D*N
constexpr int C  = 64;         // chunks per column
constexpr int S  = LL / C;     // 64 rows per chunk
constexpr int TPB = 256;       // thread owns one float4 column group

// K1: per-chunk column sums. 512 blocks x 256 thr.
__global__ __launch_bounds__(TPB) void k1(const float* __restrict__ x,
                                          float* __restrict__ csum) {
    const int bid = blockIdx.x;            // b*C + c
    const int b = bid >> 6, c = bid & (C - 1);
    const int t = threadIdx.x;
    const f4* xp = reinterpret_cast<const f4*>(
        x + (size_t)b * LL * DN + (size_t)c * S * DN) + t;
    f4 acc = (f4)0.f;
    #pragma unroll 8
    for (int i = 0; i < S; ++i) acc += xp[i * (DN / 4)];
    reinterpret_cast<f4*>(csum + (size_t)bid * DN)[t] = acc;
}

// K2: gather exclusive offset from csum, then running scan + nontemporal write.
__global__ __launch_bounds__(TPB) void k2(const float* __restrict__ x,
                                          const float* __restrict__ csum,
                                          float* __restrict__ out) {
    const int bid = blockIdx.x;
    const int b = bid >> 6, c = bid & (C - 1);
    const int t = threadIdx.x;

    // Exclusive offset: sum of this batch's preceding chunk aggregates.
    // c independent cache-resident loads, pipelined.
    f4 run = (f4)0.f;
    const f4* cs = reinterpret_cast<const f4*>(csum + (size_t)(b * C) * DN) + t;
    #pragma unroll 4
    for (int j = 0; j < c; ++j) run += cs[j * (DN / 4)];

    const size_t base = (size_t)b * LL * DN + (size_t)c * S * DN;
    const f4* xp = reinterpret_cast<const f4*>(x + base) + t;
    f4* op = reinterpret_cast<f4*>(out + base) + t;
    #pragma unroll 4
    for (int i = 0; i < S; ++i) {
        run += xp[i * (DN / 4)];
        __builtin_nontemporal_store(run, op + i * (DN / 4));
    }
}

extern "C" void kernel_launch(void* const* d_in, const int* in_sizes, int n_in,
                              void* d_out, int out_size, void* d_ws, size_t ws_size,
                              hipStream_t stream) {
    const float* x = (const float*)d_in[0];
    float* out = (float*)d_out;
    float* csum = (float*)d_ws;    // B*C*DN*4 = 2 MiB, fully overwritten by K1

    k1<<<dim3(BB * C), dim3(TPB), 0, stream>>>(x, csum);
    k2<<<dim3(BB * C), dim3(TPB), 0, stream>>>(x, csum, out);
}